// Round 17
// baseline (127.701 us; speedup 1.0000x reference)
//
#include <hip/hip_runtime.h>
#include <stdint.h>

// Problem constants (fixed by setup_inputs)
#define NROWS 8192
#define DDIM 256
#define NJ2 32             // 256-col strips
#define STRIP_COLS 256
#define BN 32              // cols per t-iteration (2 phases x 16)
#define NTILES 8           // STRIP_COLS / BN
#define BM 128             // rows per panel (4 waves x 32 rows)
#define NBLK 1056          // sum_{I=0..63} (32 - I/2) live triangular blocks

// Scores are computed directly in log2-units: e is scaled by sqrt(log2(e)/0.7)
// so acc = s*log2(e) and exp(s) == exp2(acc). Since s <= 1/0.7, exp2(acc) <= 4.17
// and per-row sums <= ~34k: no overflow, so NO log-sum-exp shift is needed at all.
#define ESCALE 1.4356159f        // sqrt(log2(e)/0.7)
#define LN2F   0.6931471806f
#define NEGBIG (-1e30f)

// Workspace layout (bytes): [0,256) accv; then DENSE partial arrays (no zero-init
// needed -- every entry kmerge reads is provably written): rowPm/rowNs [32][8192],
// colPm/colNs [64][8192]; then ebfB.
#define WS_ROWPM 256
#define WS_ROWNS (WS_ROWPM + NJ2 * NROWS * 4)
#define WS_COLPM (WS_ROWNS + NJ2 * NROWS * 4)
#define WS_COLNS (WS_COLPM + 64 * NROWS * 4)
#define WS_EBF   (WS_COLNS + 64 * NROWS * 4)

typedef __attribute__((ext_vector_type(8))) short short8;   // 8 bf16 = 4 VGPRs
typedef __attribute__((ext_vector_type(4))) float f32x4;    // MFMA 16x16 accumulator

__device__ __forceinline__ unsigned short f2bf(float x) {   // RNE float->bf16
  unsigned int u = __float_as_uint(x);
  u += 0x7fffu + ((u >> 16) & 1u);
  return (unsigned short)(u >> 16);
}

// ---------------- Kernel 1: row L2-normalize -> chunk-major bf16 (+zero accv) ----------------
// ebfB: 16B chunk (8 k-values) of row `row` at ushort offset (kc*NROWS+row)*8.
__global__ __launch_bounds__(256) void knorm(const float* __restrict__ emb,
                                             unsigned short* __restrict__ ebfB,
                                             uint4* __restrict__ accv) {
  if (blockIdx.x == 0 && threadIdx.x == 0) *accv = (uint4){0u, 0u, 0u, 0u};
  const int wave = threadIdx.x >> 6, lane = threadIdx.x & 63;
  const int row = blockIdx.x * 4 + wave;              // one wave per row
  const float4 v = *(const float4*)(emb + row * DDIM + lane * 4);
  float ss = v.x * v.x + v.y * v.y + v.z * v.z + v.w * v.w;
#pragma unroll
  for (int off = 1; off < 64; off <<= 1) ss += __shfl_xor(ss, off, 64);
  const float sc = rsqrtf(ss) * ESCALE;
  ushort4 o;
  o.x = f2bf(v.x * sc); o.y = f2bf(v.y * sc);
  o.z = f2bf(v.z * sc); o.w = f2bf(v.w * sc);
  // lane holds k = lane*4 .. lane*4+3 -> chunk kc = lane>>1, half (lane&1).
  *(ushort4*)(ebfB + ((lane >> 1) * NROWS + row) * 8 + (lane & 1) * 4) = o;
}

// ---------------- Kernel 2: symmetric, barrier-free, software-pipelined (R15 body) ----------------
// Triangular units (I = 128-row panel, J2 = 256-col strip, J2 >= I/2), R14 per-wave
// ILP pipeline (named b0/b1 double buffer, loads a phase early, no LDS staging, no
// K-loop barriers). Col path by symmetry via quad shuffles -> per-wave-private LDS
// -> single end-of-kernel barrier. Partials stored as plain floats into DENSE
// ranges: row path -> rowPm[J2][row] (J2 >= row>>8); col path -> colPm[I][col]
// (I < col>>7). Every read entry is written -> no sentinel/fkey, no zero-init.
// No min-waves bound (R4 spill); no atomics/fences in the hot loop (R6).
__global__ __launch_bounds__(256) void kmain(const unsigned short* __restrict__ ebfB,
                                             const int* __restrict__ cats,
                                             float* __restrict__ rowPm,
                                             float* __restrict__ rowNs,
                                             float* __restrict__ colPm,
                                             float* __restrict__ colNs) {
  // Decode (I, J2) from linear bid: per I there are 32 - (I>>1) strips (R9 decode).
  int bid = blockIdx.x, I = 0, base = 0;
  for (;; ++I) { const int c = NJ2 - (I >> 1); if (bid < base + c) break; base += c; }
  const int J2 = (I >> 1) + (bid - base);
  const int col0 = J2 * STRIP_COLS;
  const int t0 = (I * BM > col0) ? (NTILES / 2) : 0;  // odd-I boundary: skip 128 cols

  __shared__ float cpmL[4][STRIP_COLS], cnsL[4][STRIP_COLS];  // col partials, 8 KB
  const int tid = threadIdx.x;
  const int lane = tid & 63;
  const int lane15 = lane & 15, quad = lane >> 4;
  const int wave = tid >> 6;
  const int rowG = I * BM + wave * 32;                // this wave's 32 rows (m=2)

  // A fragments (chunk-major): a[m][kk] = rows rowG+m*16+lane15, k=kk*32+quad*8..+7.
  short8 a[2][8];
#pragma unroll
  for (int m = 0; m < 2; ++m)
#pragma unroll
    for (int kk = 0; kk < 8; ++kk)
      a[m][kk] = *(const short8*)(ebfB +
          ((size_t)(kk * 4 + quad) * NROWS + rowG + m * 16 + lane15) * 8);

  // Per-lane C-layout row categories: row = quad*4 + r (+ m*16)
  int cati[2][4];
#pragma unroll
  for (int m = 0; m < 2; ++m)
#pragma unroll
    for (int r = 0; r < 4; ++r)
      cati[m][r] = cats[rowG + m * 16 + quad * 4 + r];

  // Is this lane the diagonal element (row==col) within a diagonal 16x16 tile?
  bool dlr[4];
#pragma unroll
  for (int r = 0; r < 4; ++r) dlr[r] = (lane15 == quad * 4 + r);

  float pm[2][4], ns[2][4];
#pragma unroll
  for (int m = 0; m < 2; ++m)
#pragma unroll
    for (int r = 0; r < 4; ++r) { pm[m][r] = NEGBIG; ns[m][r] = 0.f; }

  // B-fragment base: chunk (kc = kk*4+quad, col = col0+lane15+off).
  const unsigned short* bbase = ebfB + ((size_t)quad * NROWS + col0 + lane15) * 8;

#define LOADB(buf, t, nt)                                                       \
  _Pragma("unroll")                                                             \
  for (int kk = 0; kk < 8; ++kk)                                                \
    buf[kk] = *(const short8*)(bbase +                                          \
        ((size_t)kk * 4 * NROWS + (t) * BN + (nt) * 16) * 8);

#define DOMFMA(buf, ACC0, ACC1)                                                 \
  f32x4 ACC0 = {0.f, 0.f, 0.f, 0.f}, ACC1 = {0.f, 0.f, 0.f, 0.f};              \
  _Pragma("unroll")                                                             \
  for (int kk = 0; kk < 8; ++kk) {                                              \
    ACC0 = __builtin_amdgcn_mfma_f32_16x16x32_bf16(a[0][kk], buf[kk], ACC0, 0, 0, 0); \
    ACC1 = __builtin_amdgcn_mfma_f32_16x16x32_bf16(a[1][kk], buf[kk], ACC1, 0, 0, 0); \
  }

  // Epilogue: row path (pm/ns) + col path (cpmv/cnsv by symmetry s_ij == s_ji).
#define EPI(ACC0, ACC1, t, nt)                                                  \
  {                                                                             \
    const int colBase = col0 + (t) * BN + (nt) * 16;                            \
    const int cj = cats[colBase + lane15];                                      \
    const bool dg0 = (rowG == colBase);                                         \
    const bool dg1 = (rowG + 16 == colBase);                                    \
    float cpmv = NEGBIG, cnsv = 0.f;                                            \
    _Pragma("unroll")                                                           \
    for (int m = 0; m < 2; ++m) {                                               \
      const bool dg = m ? dg1 : dg0;                                            \
      _Pragma("unroll")                                                         \
      for (int r = 0; r < 4; ++r) {                                             \
        const float s = m ? ACC1[r] : ACC0[r];      /* score in log2-units */   \
        const float e = __builtin_amdgcn_exp2f(s);                              \
        const bool same = (cj == cati[m][r]);                                   \
        float psv = same ? s : NEGBIG;                                          \
        if (dg) psv = dlr[r] ? NEGBIG : psv;        /* exclude self (rare) */   \
        pm[m][r] = fmaxf(pm[m][r], psv);                                        \
        const float ev = same ? 0.f : e;                                        \
        ns[m][r] += ev;                                                         \
        cpmv = fmaxf(cpmv, psv);                                                \
        cnsv += ev;                                                             \
      }                                                                         \
    }                                                                           \
    if ((colBase >> 7) > I) {              /* above-diagonal sub-block only */  \
      cpmv = fmaxf(cpmv, __shfl_xor(cpmv, 16, 64)); cnsv += __shfl_xor(cnsv, 16, 64); \
      cpmv = fmaxf(cpmv, __shfl_xor(cpmv, 32, 64)); cnsv += __shfl_xor(cnsv, 32, 64); \
      if (quad == 0) {                                                          \
        cpmL[wave][(t) * BN + (nt) * 16 + lane15] = cpmv;                       \
        cnsL[wave][(t) * BN + (nt) * 16 + lane15] = cnsv;                       \
      }                                                                         \
    }                                                                           \
  }

  short8 b0[8], b1[8];
  LOADB(b0, t0, 0);                        // prologue: first phase in flight

  for (int t = t0; t < NTILES; ++t) {
    LOADB(b1, t, 1);                       // issue nt=1 loads EARLY
    { DOMFMA(b0, acc0, acc1) EPI(acc0, acc1, t, 0) }   // cover for b1
    if (t + 1 < NTILES) LOADB(b0, t + 1, 0);           // issue next-t loads EARLY
    { DOMFMA(b1, acc2, acc3) EPI(acc2, acc3, t, 1) }   // cover for next b0
  }

  // Row path: reduce across the 16 lanes of each quad, store slot J2 (dense:
  // J2 >= (row>>8) always holds for this unit's rows).
#pragma unroll
  for (int off = 1; off < 16; off <<= 1) {
#pragma unroll
    for (int m = 0; m < 2; ++m)
#pragma unroll
      for (int r = 0; r < 4; ++r) {
        pm[m][r] = fmaxf(pm[m][r], __shfl_xor(pm[m][r], off, 64));
        ns[m][r] += __shfl_xor(ns[m][r], off, 64);
      }
  }
  if (lane15 == 0) {
#pragma unroll
    for (int m = 0; m < 2; ++m)
#pragma unroll
      for (int r = 0; r < 4; ++r) {
        const int row = rowG + m * 16 + quad * 4 + r;
        rowPm[J2 * NROWS + row] = pm[m][r];
        rowNs[J2 * NROWS + row] = ns[m][r];
      }
  }

  // Col path: single barrier, cross-wave combine, store slot I (dense: I < col>>7
  // for every written col). Thread c owns strip col c; active iff col0+c >= (I+1)*128.
  __syncthreads();
  const int cs = (I + 1) * BM - col0;      // cs in {<=0, 128, 256}
  if (tid >= cs) {
    const float p = fmaxf(fmaxf(cpmL[0][tid], cpmL[1][tid]),
                          fmaxf(cpmL[2][tid], cpmL[3][tid]));
    const float n = cnsL[0][tid] + cnsL[1][tid] + cnsL[2][tid] + cnsL[3][tid];
    colPm[(size_t)I * NROWS + col0 + tid] = p;
    colNs[(size_t)I * NROWS + col0 + tid] = n;
  }
}

// ---------------- Kernel 3: merge dense partials, per-row loss, finalize ----------------
__global__ __launch_bounds__(256) void kmerge(const float* __restrict__ rowPm,
                                              const float* __restrict__ rowNs,
                                              const float* __restrict__ colPm,
                                              const float* __restrict__ colNs,
                                              float* __restrict__ acc,
                                              float* __restrict__ out) {
  const int row = blockIdx.x * 256 + threadIdx.x;
  float pm = NEGBIG, ns = 0.f;
  // Row-path slots: dense suffix J2 in [row>>8, 32).
  for (int s = row >> 8; s < NJ2; ++s) {
    pm = fmaxf(pm, rowPm[s * NROWS + row]);
    ns += rowNs[s * NROWS + row];
  }
  // Col-path slots: dense prefix I in [0, row>>7)  (row acts as a column here).
  const int iN = row >> 7;
  for (int s = 0; s < iN; ++s) {
    pm = fmaxf(pm, colPm[(size_t)s * NROWS + row]);
    ns += colNs[(size_t)s * NROWS + row];
  }
  const bool valid = (pm > -1e29f) && (ns > 0.f);
  // pm is pos*log2(e); loss = -pos + ln(exp2(pm) + sum_neg exp(s))   (no shift needed)
  float loss = valid ? (logf(__builtin_amdgcn_exp2f(pm) + ns) - pm * LN2F) : 0.f;
  float cnt = valid ? 1.f : 0.f;
#pragma unroll
  for (int off = 1; off < 64; off <<= 1) {
    loss += __shfl_xor(loss, off, 64);
    cnt += __shfl_xor(cnt, off, 64);
  }
  if ((threadIdx.x & 63) == 0) {
    atomicAdd(&acc[0], loss);
    atomicAdd(&acc[1], cnt);
    __threadfence();                       // my adds visible before the counter bump
  }
  __syncthreads();
  if (threadIdx.x == 0) {
    const int prev = atomicAdd((int*)(acc + 2), 1);
    if (prev == (int)gridDim.x - 1) {      // last block finalizes
      const float L = atomicAdd(&acc[0], 0.f);   // coherent reads
      const float C = atomicAdd(&acc[1], 0.f);
      out[0] = L / fmaxf(C, 1.f);
    }
  }
}

// ---------------- Launch ----------------
extern "C" void kernel_launch(void* const* d_in, const int* in_sizes, int n_in,
                              void* d_out, int out_size, void* d_ws, size_t ws_size,
                              hipStream_t stream) {
  const float* emb = (const float*)d_in[0];
  const int* cats = (const int*)d_in[1];
  // d_in[2] (font_labels) is unused by the reference.
  float* out = (float*)d_out;

  char* ws = (char*)d_ws;
  float* accv = (float*)ws;                                  // loss, cnt, block counter
  float* rowPm = (float*)(ws + WS_ROWPM);
  float* rowNs = (float*)(ws + WS_ROWNS);
  float* colPm = (float*)(ws + WS_COLPM);
  float* colNs = (float*)(ws + WS_COLNS);
  unsigned short* ebfB = (unsigned short*)(ws + WS_EBF);     // 4 MB chunk-major bf16

  knorm<<<NROWS / 4, 256, 0, stream>>>(emb, ebfB, (uint4*)ws);
  kmain<<<NBLK, 256, 0, stream>>>(ebfB, cats, rowPm, rowNs, colPm, colNs);
  kmerge<<<NROWS / 256, 256, 0, stream>>>(rowPm, rowNs, colPm, colNs, accv, out);
}

// Round 18
// 125.161 us; speedup vs baseline: 1.0203x; 1.0203x over previous
//
#include <hip/hip_runtime.h>
#include <stdint.h>

// Problem constants (fixed by setup_inputs)
#define NROWS 8192
#define DDIM 256
#define NJ2 32             // 256-col strips
#define STRIP_COLS 256
#define BN 32              // cols per t-iteration (2 phases x 16)
#define NTILES 8           // STRIP_COLS / BN
#define BM 128             // rows per panel (4 waves x 32 rows)
#define NBLK 1056          // sum_{I=0..63} (32 - I/2) live triangular blocks

// Scores are computed directly in log2-units: e is scaled by sqrt(log2(e)/0.7)
// so acc = s*log2(e) and exp(s) == exp2(acc). Since s <= 1/0.7, exp2(acc) <= 4.17
// and per-row sums <= ~34k: no overflow, so NO log-sum-exp shift is needed at all.
#define ESCALE 1.4356159f        // sqrt(log2(e)/0.7)
#define LN2F   0.6931471806f
#define NEGBIG (-1e30f)

// Workspace layout (bytes): [0,256) accv; then DENSE partial arrays (no zero-init
// needed -- every entry kmerge reads is provably written): rowPm/rowNs [32][8192],
// colPm/colNs [64][8192]; then ebfB.
#define WS_ROWPM 256
#define WS_ROWNS (WS_ROWPM + NJ2 * NROWS * 4)
#define WS_COLPM (WS_ROWNS + NJ2 * NROWS * 4)
#define WS_COLNS (WS_COLPM + 64 * NROWS * 4)
#define WS_EBF   (WS_COLNS + 64 * NROWS * 4)

typedef __attribute__((ext_vector_type(8))) short short8;   // 8 bf16 = 4 VGPRs
typedef __attribute__((ext_vector_type(4))) float f32x4;    // MFMA 16x16 accumulator

__device__ __forceinline__ unsigned short f2bf(float x) {   // RNE float->bf16
  unsigned int u = __float_as_uint(x);
  u += 0x7fffu + ((u >> 16) & 1u);
  return (unsigned short)(u >> 16);
}

// ---------------- Kernel 1: row L2-normalize -> chunk-major bf16 (+zero accv) ----------------
// ebfB: 16B chunk (8 k-values) of row `row` at ushort offset (kc*NROWS+row)*8.
__global__ __launch_bounds__(256) void knorm(const float* __restrict__ emb,
                                             unsigned short* __restrict__ ebfB,
                                             uint4* __restrict__ accv) {
  if (blockIdx.x == 0 && threadIdx.x == 0) *accv = (uint4){0u, 0u, 0u, 0u};
  const int wave = threadIdx.x >> 6, lane = threadIdx.x & 63;
  const int row = blockIdx.x * 4 + wave;              // one wave per row
  const float4 v = *(const float4*)(emb + row * DDIM + lane * 4);
  float ss = v.x * v.x + v.y * v.y + v.z * v.z + v.w * v.w;
#pragma unroll
  for (int off = 1; off < 64; off <<= 1) ss += __shfl_xor(ss, off, 64);
  const float sc = rsqrtf(ss) * ESCALE;
  ushort4 o;
  o.x = f2bf(v.x * sc); o.y = f2bf(v.y * sc);
  o.z = f2bf(v.z * sc); o.w = f2bf(v.w * sc);
  // lane holds k = lane*4 .. lane*4+3 -> chunk kc = lane>>1, half (lane&1).
  *(ushort4*)(ebfB + ((lane >> 1) * NROWS + row) * 8 + (lane & 1) * 4) = o;
}

// ---------------- Kernel 2: symmetric, barrier-free, software-pipelined ----------------
// R17 body + two stall fixes: (1) SPLIT ACCUMULATOR CHAINS -- each DOMFMA now runs
// 4 independent MFMA dependency chains (even/odd kk) instead of 2 serial 8-deep
// chains, halving the dependent-MFMA latency exposure on the matrix pipe;
// (2) category loads cj0/cj1 hoisted to loop-top so they get the same one-phase
// cover as the b-fragments (were loaded inside EPI right before use).
// No min-waves bound (R4 spill); no atomics/fences in the hot loop (R6).
__global__ __launch_bounds__(256) void kmain(const unsigned short* __restrict__ ebfB,
                                             const int* __restrict__ cats,
                                             float* __restrict__ rowPm,
                                             float* __restrict__ rowNs,
                                             float* __restrict__ colPm,
                                             float* __restrict__ colNs) {
  // Decode (I, J2) from linear bid: per I there are 32 - (I>>1) strips (R9 decode).
  int bid = blockIdx.x, I = 0, base = 0;
  for (;; ++I) { const int c = NJ2 - (I >> 1); if (bid < base + c) break; base += c; }
  const int J2 = (I >> 1) + (bid - base);
  const int col0 = J2 * STRIP_COLS;
  const int t0 = (I * BM > col0) ? (NTILES / 2) : 0;  // odd-I boundary: skip 128 cols

  __shared__ float cpmL[4][STRIP_COLS], cnsL[4][STRIP_COLS];  // col partials, 8 KB
  const int tid = threadIdx.x;
  const int lane = tid & 63;
  const int lane15 = lane & 15, quad = lane >> 4;
  const int wave = tid >> 6;
  const int rowG = I * BM + wave * 32;                // this wave's 32 rows (m=2)

  // A fragments (chunk-major): a[m][kk] = rows rowG+m*16+lane15, k=kk*32+quad*8..+7.
  short8 a[2][8];
#pragma unroll
  for (int m = 0; m < 2; ++m)
#pragma unroll
    for (int kk = 0; kk < 8; ++kk)
      a[m][kk] = *(const short8*)(ebfB +
          ((size_t)(kk * 4 + quad) * NROWS + rowG + m * 16 + lane15) * 8);

  // Per-lane C-layout row categories: row = quad*4 + r (+ m*16)
  int cati[2][4];
#pragma unroll
  for (int m = 0; m < 2; ++m)
#pragma unroll
    for (int r = 0; r < 4; ++r)
      cati[m][r] = cats[rowG + m * 16 + quad * 4 + r];

  // Is this lane the diagonal element (row==col) within a diagonal 16x16 tile?
  bool dlr[4];
#pragma unroll
  for (int r = 0; r < 4; ++r) dlr[r] = (lane15 == quad * 4 + r);

  float pm[2][4], ns[2][4];
#pragma unroll
  for (int m = 0; m < 2; ++m)
#pragma unroll
    for (int r = 0; r < 4; ++r) { pm[m][r] = NEGBIG; ns[m][r] = 0.f; }

  // B-fragment base: chunk (kc = kk*4+quad, col = col0+lane15+off).
  const unsigned short* bbase = ebfB + ((size_t)quad * NROWS + col0 + lane15) * 8;

#define LOADB(buf, t, nt)                                                       \
  _Pragma("unroll")                                                             \
  for (int kk = 0; kk < 8; ++kk)                                                \
    buf[kk] = *(const short8*)(bbase +                                          \
        ((size_t)kk * 4 * NROWS + (t) * BN + (nt) * 16) * 8);

  // 4 independent MFMA chains (even/odd kk split), merged by one vector add:
  // dependent-MFMA latency is hidden by round-robin issue across the chains.
#define DOMFMA(buf, ACC0, ACC1)                                                 \
  f32x4 ACC0 = {0.f, 0.f, 0.f, 0.f}, ACC1 = {0.f, 0.f, 0.f, 0.f};              \
  {                                                                             \
    f32x4 x0 = {0.f, 0.f, 0.f, 0.f}, x1 = {0.f, 0.f, 0.f, 0.f};                \
    _Pragma("unroll")                                                           \
    for (int kk = 0; kk < 8; kk += 2) {                                         \
      ACC0 = __builtin_amdgcn_mfma_f32_16x16x32_bf16(a[0][kk], buf[kk], ACC0, 0, 0, 0);     \
      ACC1 = __builtin_amdgcn_mfma_f32_16x16x32_bf16(a[1][kk], buf[kk], ACC1, 0, 0, 0);     \
      x0   = __builtin_amdgcn_mfma_f32_16x16x32_bf16(a[0][kk + 1], buf[kk + 1], x0, 0, 0, 0); \
      x1   = __builtin_amdgcn_mfma_f32_16x16x32_bf16(a[1][kk + 1], buf[kk + 1], x1, 0, 0, 0); \
    }                                                                           \
    ACC0 += x0; ACC1 += x1;                                                     \
  }

  // Epilogue: row path (pm/ns) + col path (cpmv/cnsv by symmetry s_ij == s_ji).
  // cj passed in (hoisted load -- one-phase cover).
#define EPI(ACC0, ACC1, t, nt, CJ)                                              \
  {                                                                             \
    const int colBase = col0 + (t) * BN + (nt) * 16;                            \
    const bool dg0 = (rowG == colBase);                                         \
    const bool dg1 = (rowG + 16 == colBase);                                    \
    float cpmv = NEGBIG, cnsv = 0.f;                                            \
    _Pragma("unroll")                                                           \
    for (int m = 0; m < 2; ++m) {                                               \
      const bool dg = m ? dg1 : dg0;                                            \
      _Pragma("unroll")                                                         \
      for (int r = 0; r < 4; ++r) {                                             \
        const float s = m ? ACC1[r] : ACC0[r];      /* score in log2-units */   \
        const float e = __builtin_amdgcn_exp2f(s);                              \
        const bool same = ((CJ) == cati[m][r]);                                 \
        float psv = same ? s : NEGBIG;                                          \
        if (dg) psv = dlr[r] ? NEGBIG : psv;        /* exclude self (rare) */   \
        pm[m][r] = fmaxf(pm[m][r], psv);                                        \
        const float ev = same ? 0.f : e;                                        \
        ns[m][r] += ev;                                                         \
        cpmv = fmaxf(cpmv, psv);                                                \
        cnsv += ev;                                                             \
      }                                                                         \
    }                                                                           \
    if ((colBase >> 7) > I) {              /* above-diagonal sub-block only */  \
      cpmv = fmaxf(cpmv, __shfl_xor(cpmv, 16, 64)); cnsv += __shfl_xor(cnsv, 16, 64); \
      cpmv = fmaxf(cpmv, __shfl_xor(cpmv, 32, 64)); cnsv += __shfl_xor(cnsv, 32, 64); \
      if (quad == 0) {                                                          \
        cpmL[wave][(t) * BN + (nt) * 16 + lane15] = cpmv;                       \
        cnsL[wave][(t) * BN + (nt) * 16 + lane15] = cnsv;                       \
      }                                                                         \
    }                                                                           \
  }

  short8 b0[8], b1[8];
  LOADB(b0, t0, 0);                        // prologue: first phase in flight

  for (int t = t0; t < NTILES; ++t) {
    const int cj0 = cats[col0 + t * BN + lane15];        // hoisted: one-phase cover
    const int cj1 = cats[col0 + t * BN + 16 + lane15];
    LOADB(b1, t, 1);                       // issue nt=1 loads EARLY
    { DOMFMA(b0, acc0, acc1) EPI(acc0, acc1, t, 0, cj0) }   // cover for b1
    if (t + 1 < NTILES) LOADB(b0, t + 1, 0);                // issue next-t loads EARLY
    { DOMFMA(b1, acc2, acc3) EPI(acc2, acc3, t, 1, cj1) }   // cover for next b0
  }

  // Row path: reduce across the 16 lanes of each quad, store slot J2 (dense:
  // J2 >= (row>>8) always holds for this unit's rows).
#pragma unroll
  for (int off = 1; off < 16; off <<= 1) {
#pragma unroll
    for (int m = 0; m < 2; ++m)
#pragma unroll
      for (int r = 0; r < 4; ++r) {
        pm[m][r] = fmaxf(pm[m][r], __shfl_xor(pm[m][r], off, 64));
        ns[m][r] += __shfl_xor(ns[m][r], off, 64);
      }
  }
  if (lane15 == 0) {
#pragma unroll
    for (int m = 0; m < 2; ++m)
#pragma unroll
      for (int r = 0; r < 4; ++r) {
        const int row = rowG + m * 16 + quad * 4 + r;
        rowPm[J2 * NROWS + row] = pm[m][r];
        rowNs[J2 * NROWS + row] = ns[m][r];
      }
  }

  // Col path: single barrier, cross-wave combine, store slot I (dense: I < col>>7
  // for every written col). Thread c owns strip col c; active iff col0+c >= (I+1)*128.
  __syncthreads();
  const int cs = (I + 1) * BM - col0;      // cs in {<=0, 128, 256}
  if (tid >= cs) {
    const float p = fmaxf(fmaxf(cpmL[0][tid], cpmL[1][tid]),
                          fmaxf(cpmL[2][tid], cpmL[3][tid]));
    const float n = cnsL[0][tid] + cnsL[1][tid] + cnsL[2][tid] + cnsL[3][tid];
    colPm[(size_t)I * NROWS + col0 + tid] = p;
    colNs[(size_t)I * NROWS + col0 + tid] = n;
  }
}

// ---------------- Kernel 3: merge dense partials, per-row loss, finalize ----------------
__global__ __launch_bounds__(256) void kmerge(const float* __restrict__ rowPm,
                                              const float* __restrict__ rowNs,
                                              const float* __restrict__ colPm,
                                              const float* __restrict__ colNs,
                                              float* __restrict__ acc,
                                              float* __restrict__ out) {
  const int row = blockIdx.x * 256 + threadIdx.x;
  float pm = NEGBIG, ns = 0.f;
  // Row-path slots: dense suffix J2 in [row>>8, 32).
  for (int s = row >> 8; s < NJ2; ++s) {
    pm = fmaxf(pm, rowPm[s * NROWS + row]);
    ns += rowNs[s * NROWS + row];
  }
  // Col-path slots: dense prefix I in [0, row>>7)  (row acts as a column here).
  const int iN = row >> 7;
  for (int s = 0; s < iN; ++s) {
    pm = fmaxf(pm, colPm[(size_t)s * NROWS + row]);
    ns += colNs[(size_t)s * NROWS + row];
  }
  const bool valid = (pm > -1e29f) && (ns > 0.f);
  // pm is pos*log2(e); loss = -pos + ln(exp2(pm) + sum_neg exp(s))   (no shift needed)
  float loss = valid ? (logf(__builtin_amdgcn_exp2f(pm) + ns) - pm * LN2F) : 0.f;
  float cnt = valid ? 1.f : 0.f;
#pragma unroll
  for (int off = 1; off < 64; off <<= 1) {
    loss += __shfl_xor(loss, off, 64);
    cnt += __shfl_xor(cnt, off, 64);
  }
  if ((threadIdx.x & 63) == 0) {
    atomicAdd(&acc[0], loss);
    atomicAdd(&acc[1], cnt);
    __threadfence();                       // my adds visible before the counter bump
  }
  __syncthreads();
  if (threadIdx.x == 0) {
    const int prev = atomicAdd((int*)(acc + 2), 1);
    if (prev == (int)gridDim.x - 1) {      // last block finalizes
      const float L = atomicAdd(&acc[0], 0.f);   // coherent reads
      const float C = atomicAdd(&acc[1], 0.f);
      out[0] = L / fmaxf(C, 1.f);
    }
  }
}

// ---------------- Launch ----------------
extern "C" void kernel_launch(void* const* d_in, const int* in_sizes, int n_in,
                              void* d_out, int out_size, void* d_ws, size_t ws_size,
                              hipStream_t stream) {
  const float* emb = (const float*)d_in[0];
  const int* cats = (const int*)d_in[1];
  // d_in[2] (font_labels) is unused by the reference.
  float* out = (float*)d_out;

  char* ws = (char*)d_ws;
  float* accv = (float*)ws;                                  // loss, cnt, block counter
  float* rowPm = (float*)(ws + WS_ROWPM);
  float* rowNs = (float*)(ws + WS_ROWNS);
  float* colPm = (float*)(ws + WS_COLPM);
  float* colNs = (float*)(ws + WS_COLNS);
  unsigned short* ebfB = (unsigned short*)(ws + WS_EBF);     // 4 MB chunk-major bf16

  knorm<<<NROWS / 4, 256, 0, stream>>>(emb, ebfB, (uint4*)ws);
  kmain<<<NBLK, 256, 0, stream>>>(ebfB, cats, rowPm, rowNs, colPm, colNs);
  kmerge<<<NROWS / 256, 256, 0, stream>>>(rowPm, rowNs, colPm, colNs, accv, out);
}

// Round 19
// 123.711 us; speedup vs baseline: 1.0323x; 1.0117x over previous
//
#include <hip/hip_runtime.h>
#include <stdint.h>

// Problem constants (fixed by setup_inputs)
#define NROWS 8192
#define DDIM 256
#define NJ2 32             // 256-col strips
#define STRIP_COLS 256
#define BN 32              // cols per t-iteration (2 phases x 16)
#define NTILES 8           // STRIP_COLS / BN
#define BM 128             // rows per panel (4 waves x 32 rows)
#define NBLK 1056          // sum_{I=0..63} (32 - I/2) live triangular blocks

// Scores are computed directly in log2-units: e is scaled by sqrt(log2(e)/0.7)
// so acc = s*log2(e) and exp(s) == exp2(acc). Since s <= 1/0.7, exp2(acc) <= 4.17
// and per-row sums <= ~34k: no overflow, so NO log-sum-exp shift is needed at all.
#define ESCALE 1.4356159f        // sqrt(log2(e)/0.7)
#define LN2F   0.6931471806f
#define NEGBIG (-1e30f)

// Workspace layout (bytes): [0,256) accv; then bf16-PACKED dense partial arrays
// (u32 = bf16(pm)<<16 | bf16(ns); every entry kmerge reads is provably written):
// rowP [32][8192], colP [64][8192]; then ebfB. Total ~7.2 MB (was 10.2 -- the
// session residue correlates with ws bytes; this is the cheapest test of that).
#define WS_ROWP  256
#define WS_COLP  (WS_ROWP + NJ2 * NROWS * 4)
#define WS_EBF   (WS_COLP + 64 * NROWS * 4)

typedef __attribute__((ext_vector_type(8))) short short8;   // 8 bf16 = 4 VGPRs
typedef __attribute__((ext_vector_type(4))) float f32x4;    // MFMA 16x16 accumulator

__device__ __forceinline__ unsigned short f2bf(float x) {   // RNE float->bf16
  unsigned int u = __float_as_uint(x);
  u += 0x7fffu + ((u >> 16) & 1u);
  return (unsigned short)(u >> 16);
}
__device__ __forceinline__ float bf2f(unsigned short b) {
  return __uint_as_float((unsigned)b << 16);
}
__device__ __forceinline__ unsigned packPN(float pm, float ns) {
  return ((unsigned)f2bf(pm) << 16) | f2bf(ns);
}

// ---------------- Kernel 1: row L2-normalize -> chunk-major bf16 (+zero accv) ----------------
// ebfB: 16B chunk (8 k-values) of row `row` at ushort offset (kc*NROWS+row)*8.
__global__ __launch_bounds__(256) void knorm(const float* __restrict__ emb,
                                             unsigned short* __restrict__ ebfB,
                                             uint4* __restrict__ accv) {
  if (blockIdx.x == 0 && threadIdx.x == 0) *accv = (uint4){0u, 0u, 0u, 0u};
  const int wave = threadIdx.x >> 6, lane = threadIdx.x & 63;
  const int row = blockIdx.x * 4 + wave;              // one wave per row
  const float4 v = *(const float4*)(emb + row * DDIM + lane * 4);
  float ss = v.x * v.x + v.y * v.y + v.z * v.z + v.w * v.w;
#pragma unroll
  for (int off = 1; off < 64; off <<= 1) ss += __shfl_xor(ss, off, 64);
  const float sc = rsqrtf(ss) * ESCALE;
  ushort4 o;
  o.x = f2bf(v.x * sc); o.y = f2bf(v.y * sc);
  o.z = f2bf(v.z * sc); o.w = f2bf(v.w * sc);
  // lane holds k = lane*4 .. lane*4+3 -> chunk kc = lane>>1, half (lane&1).
  *(ushort4*)(ebfB + ((lane >> 1) * NROWS + row) * 8 + (lane & 1) * 4) = o;
}

// ---------------- Kernel 2: symmetric, barrier-free, software-pipelined ----------------
// Verified 45us body (R18): triangular units (I, J2 >= I/2), per-wave ILP pipeline
// (named b0/b1 double buffer, loads a phase early, no LDS staging, no K-loop
// barriers), 4 independent MFMA chains, hoisted category loads, col path by
// symmetry via quad shuffles -> per-wave-private LDS -> single end barrier.
// Partials stored bf16-PACKED into dense ranges: rowP[J2][row] (J2 >= row>>8),
// colP[I][col] (I < col>>7). No sentinel, no zero-init, no atomics/fences (R6),
// no min-waves bound (R4).
__global__ __launch_bounds__(256) void kmain(const unsigned short* __restrict__ ebfB,
                                             const int* __restrict__ cats,
                                             unsigned* __restrict__ rowP,
                                             unsigned* __restrict__ colP) {
  // Decode (I, J2) from linear bid: per I there are 32 - (I>>1) strips (R9 decode).
  int bid = blockIdx.x, I = 0, base = 0;
  for (;; ++I) { const int c = NJ2 - (I >> 1); if (bid < base + c) break; base += c; }
  const int J2 = (I >> 1) + (bid - base);
  const int col0 = J2 * STRIP_COLS;
  const int t0 = (I * BM > col0) ? (NTILES / 2) : 0;  // odd-I boundary: skip 128 cols

  __shared__ float cpmL[4][STRIP_COLS], cnsL[4][STRIP_COLS];  // col partials, 8 KB
  const int tid = threadIdx.x;
  const int lane = tid & 63;
  const int lane15 = lane & 15, quad = lane >> 4;
  const int wave = tid >> 6;
  const int rowG = I * BM + wave * 32;                // this wave's 32 rows (m=2)

  // A fragments (chunk-major): a[m][kk] = rows rowG+m*16+lane15, k=kk*32+quad*8..+7.
  short8 a[2][8];
#pragma unroll
  for (int m = 0; m < 2; ++m)
#pragma unroll
    for (int kk = 0; kk < 8; ++kk)
      a[m][kk] = *(const short8*)(ebfB +
          ((size_t)(kk * 4 + quad) * NROWS + rowG + m * 16 + lane15) * 8);

  // Per-lane C-layout row categories: row = quad*4 + r (+ m*16)
  int cati[2][4];
#pragma unroll
  for (int m = 0; m < 2; ++m)
#pragma unroll
    for (int r = 0; r < 4; ++r)
      cati[m][r] = cats[rowG + m * 16 + quad * 4 + r];

  // Is this lane the diagonal element (row==col) within a diagonal 16x16 tile?
  bool dlr[4];
#pragma unroll
  for (int r = 0; r < 4; ++r) dlr[r] = (lane15 == quad * 4 + r);

  float pm[2][4], ns[2][4];
#pragma unroll
  for (int m = 0; m < 2; ++m)
#pragma unroll
    for (int r = 0; r < 4; ++r) { pm[m][r] = NEGBIG; ns[m][r] = 0.f; }

  // B-fragment base: chunk (kc = kk*4+quad, col = col0+lane15+off).
  const unsigned short* bbase = ebfB + ((size_t)quad * NROWS + col0 + lane15) * 8;

#define LOADB(buf, t, nt)                                                       \
  _Pragma("unroll")                                                             \
  for (int kk = 0; kk < 8; ++kk)                                                \
    buf[kk] = *(const short8*)(bbase +                                          \
        ((size_t)kk * 4 * NROWS + (t) * BN + (nt) * 16) * 8);

  // 4 independent MFMA chains (even/odd kk split), merged by one vector add.
#define DOMFMA(buf, ACC0, ACC1)                                                 \
  f32x4 ACC0 = {0.f, 0.f, 0.f, 0.f}, ACC1 = {0.f, 0.f, 0.f, 0.f};              \
  {                                                                             \
    f32x4 x0 = {0.f, 0.f, 0.f, 0.f}, x1 = {0.f, 0.f, 0.f, 0.f};                \
    _Pragma("unroll")                                                           \
    for (int kk = 0; kk < 8; kk += 2) {                                         \
      ACC0 = __builtin_amdgcn_mfma_f32_16x16x32_bf16(a[0][kk], buf[kk], ACC0, 0, 0, 0);     \
      ACC1 = __builtin_amdgcn_mfma_f32_16x16x32_bf16(a[1][kk], buf[kk], ACC1, 0, 0, 0);     \
      x0   = __builtin_amdgcn_mfma_f32_16x16x32_bf16(a[0][kk + 1], buf[kk + 1], x0, 0, 0, 0); \
      x1   = __builtin_amdgcn_mfma_f32_16x16x32_bf16(a[1][kk + 1], buf[kk + 1], x1, 0, 0, 0); \
    }                                                                           \
    ACC0 += x0; ACC1 += x1;                                                     \
  }

  // Epilogue: row path (pm/ns) + col path (cpmv/cnsv by symmetry s_ij == s_ji).
#define EPI(ACC0, ACC1, t, nt, CJ)                                              \
  {                                                                             \
    const int colBase = col0 + (t) * BN + (nt) * 16;                            \
    const bool dg0 = (rowG == colBase);                                         \
    const bool dg1 = (rowG + 16 == colBase);                                    \
    float cpmv = NEGBIG, cnsv = 0.f;                                            \
    _Pragma("unroll")                                                           \
    for (int m = 0; m < 2; ++m) {                                               \
      const bool dg = m ? dg1 : dg0;                                            \
      _Pragma("unroll")                                                         \
      for (int r = 0; r < 4; ++r) {                                             \
        const float s = m ? ACC1[r] : ACC0[r];      /* score in log2-units */   \
        const float e = __builtin_amdgcn_exp2f(s);                              \
        const bool same = ((CJ) == cati[m][r]);                                 \
        float psv = same ? s : NEGBIG;                                          \
        if (dg) psv = dlr[r] ? NEGBIG : psv;        /* exclude self (rare) */   \
        pm[m][r] = fmaxf(pm[m][r], psv);                                        \
        const float ev = same ? 0.f : e;                                        \
        ns[m][r] += ev;                                                         \
        cpmv = fmaxf(cpmv, psv);                                                \
        cnsv += ev;                                                             \
      }                                                                         \
    }                                                                           \
    if ((colBase >> 7) > I) {              /* above-diagonal sub-block only */  \
      cpmv = fmaxf(cpmv, __shfl_xor(cpmv, 16, 64)); cnsv += __shfl_xor(cnsv, 16, 64); \
      cpmv = fmaxf(cpmv, __shfl_xor(cpmv, 32, 64)); cnsv += __shfl_xor(cnsv, 32, 64); \
      if (quad == 0) {                                                          \
        cpmL[wave][(t) * BN + (nt) * 16 + lane15] = cpmv;                       \
        cnsL[wave][(t) * BN + (nt) * 16 + lane15] = cnsv;                       \
      }                                                                         \
    }                                                                           \
  }

  short8 b0[8], b1[8];
  LOADB(b0, t0, 0);                        // prologue: first phase in flight

  for (int t = t0; t < NTILES; ++t) {
    const int cj0 = cats[col0 + t * BN + lane15];        // hoisted: one-phase cover
    const int cj1 = cats[col0 + t * BN + 16 + lane15];
    LOADB(b1, t, 1);                       // issue nt=1 loads EARLY
    { DOMFMA(b0, acc0, acc1) EPI(acc0, acc1, t, 0, cj0) }   // cover for b1
    if (t + 1 < NTILES) LOADB(b0, t + 1, 0);                // issue next-t loads EARLY
    { DOMFMA(b1, acc2, acc3) EPI(acc2, acc3, t, 1, cj1) }   // cover for next b0
  }

  // Row path: reduce across the 16 lanes of each quad, store packed slot J2
  // (dense: J2 >= (row>>8) always holds for this unit's rows).
#pragma unroll
  for (int off = 1; off < 16; off <<= 1) {
#pragma unroll
    for (int m = 0; m < 2; ++m)
#pragma unroll
      for (int r = 0; r < 4; ++r) {
        pm[m][r] = fmaxf(pm[m][r], __shfl_xor(pm[m][r], off, 64));
        ns[m][r] += __shfl_xor(ns[m][r], off, 64);
      }
  }
  if (lane15 == 0) {
#pragma unroll
    for (int m = 0; m < 2; ++m)
#pragma unroll
      for (int r = 0; r < 4; ++r) {
        const int row = rowG + m * 16 + quad * 4 + r;
        rowP[J2 * NROWS + row] = packPN(pm[m][r], ns[m][r]);
      }
  }

  // Col path: single barrier, cross-wave combine, store packed slot I (dense:
  // I < col>>7 for every written col). Thread c owns strip col c.
  __syncthreads();
  const int cs = (I + 1) * BM - col0;      // cs in {<=0, 128, 256}
  if (tid >= cs) {
    const float p = fmaxf(fmaxf(cpmL[0][tid], cpmL[1][tid]),
                          fmaxf(cpmL[2][tid], cpmL[3][tid]));
    const float n = cnsL[0][tid] + cnsL[1][tid] + cnsL[2][tid] + cnsL[3][tid];
    colP[(size_t)I * NROWS + col0 + tid] = packPN(p, n);
  }
}

// ---------------- Kernel 3: merge packed dense partials, per-row loss, finalize ----------------
__global__ __launch_bounds__(256) void kmerge(const unsigned* __restrict__ rowP,
                                              const unsigned* __restrict__ colP,
                                              float* __restrict__ acc,
                                              float* __restrict__ out) {
  const int row = blockIdx.x * 256 + threadIdx.x;
  float pm = NEGBIG, ns = 0.f;
  // Row-path slots: dense suffix J2 in [row>>8, 32).
  for (int s = row >> 8; s < NJ2; ++s) {
    const unsigned u = rowP[s * NROWS + row];
    pm = fmaxf(pm, bf2f((unsigned short)(u >> 16)));
    ns += bf2f((unsigned short)(u & 0xffffu));
  }
  // Col-path slots: dense prefix I in [0, row>>7)  (row acts as a column here).
  const int iN = row >> 7;
  for (int s = 0; s < iN; ++s) {
    const unsigned u = colP[(size_t)s * NROWS + row];
    pm = fmaxf(pm, bf2f((unsigned short)(u >> 16)));
    ns += bf2f((unsigned short)(u & 0xffffu));
  }
  const bool valid = (pm > -1e29f) && (ns > 0.f);
  // pm is pos*log2(e); loss = -pos + ln(exp2(pm) + sum_neg exp(s))   (no shift needed)
  float loss = valid ? (logf(__builtin_amdgcn_exp2f(pm) + ns) - pm * LN2F) : 0.f;
  float cnt = valid ? 1.f : 0.f;
#pragma unroll
  for (int off = 1; off < 64; off <<= 1) {
    loss += __shfl_xor(loss, off, 64);
    cnt += __shfl_xor(cnt, off, 64);
  }
  if ((threadIdx.x & 63) == 0) {
    atomicAdd(&acc[0], loss);
    atomicAdd(&acc[1], cnt);
    __threadfence();                       // my adds visible before the counter bump
  }
  __syncthreads();
  if (threadIdx.x == 0) {
    const int prev = atomicAdd((int*)(acc + 2), 1);
    if (prev == (int)gridDim.x - 1) {      // last block finalizes
      const float L = atomicAdd(&acc[0], 0.f);   // coherent reads
      const float C = atomicAdd(&acc[1], 0.f);
      out[0] = L / fmaxf(C, 1.f);
    }
  }
}

// ---------------- Launch ----------------
extern "C" void kernel_launch(void* const* d_in, const int* in_sizes, int n_in,
                              void* d_out, int out_size, void* d_ws, size_t ws_size,
                              hipStream_t stream) {
  const float* emb = (const float*)d_in[0];
  const int* cats = (const int*)d_in[1];
  // d_in[2] (font_labels) is unused by the reference.
  float* out = (float*)d_out;

  char* ws = (char*)d_ws;
  float* accv = (float*)ws;                                  // loss, cnt, block counter
  unsigned* rowP = (unsigned*)(ws + WS_ROWP);                // packed row partials
  unsigned* colP = (unsigned*)(ws + WS_COLP);                // packed col partials
  unsigned short* ebfB = (unsigned short*)(ws + WS_EBF);     // 4 MB chunk-major bf16

  knorm<<<NROWS / 4, 256, 0, stream>>>(emb, ebfB, (uint4*)ws);
  kmain<<<NBLK, 256, 0, stream>>>(ebfB, cats, rowP, colP);
  kmerge<<<NROWS / 256, 256, 0, stream>>>(rowP, colP, accv, out);
}